// Round 7
// baseline (352.244 us; speedup 1.0000x reference)
//
#include <hip/hip_runtime.h>
#include <math.h>

// global -> LDS async DMA (size literal; LDS dest = wave-uniform base + lane*size)
#define GLL16(gp, lp_)                                                     \
  __builtin_amdgcn_global_load_lds(                                        \
      (const __attribute__((address_space(1))) void*)(gp),                 \
      (__attribute__((address_space(3))) void*)(lp_), 16, 0, 0)
#define GLL4(gp, lp_)                                                      \
  __builtin_amdgcn_global_load_lds(                                        \
      (const __attribute__((address_space(1))) void*)(gp),                 \
      (__attribute__((address_space(3))) void*)(lp_), 4, 0, 0)
#define SB() __builtin_amdgcn_sched_barrier(0)

__device__ inline float wave_max64(float v) {
#pragma unroll
  for (int off = 32; off > 0; off >>= 1) v = fmaxf(v, __shfl_xor(v, off, 64));
  return v;
}
__device__ inline float wave_sum64(float v) {
#pragma unroll
  for (int off = 32; off > 0; off >>= 1) v += __shfl_xor(v, off, 64);
  return v;
}
// wave64 max via DPP, result broadcast (verified rounds 4-6)
__device__ inline float wave_max_dpp(float x) {
  int xi = __float_as_int(x);
  x = fmaxf(x, __int_as_float(__builtin_amdgcn_update_dpp(xi, xi, 0x111, 0xf, 0xf, false)));
  xi = __float_as_int(x);
  x = fmaxf(x, __int_as_float(__builtin_amdgcn_update_dpp(xi, xi, 0x112, 0xf, 0xf, false)));
  xi = __float_as_int(x);
  x = fmaxf(x, __int_as_float(__builtin_amdgcn_update_dpp(xi, xi, 0x114, 0xf, 0xf, false)));
  xi = __float_as_int(x);
  x = fmaxf(x, __int_as_float(__builtin_amdgcn_update_dpp(xi, xi, 0x118, 0xf, 0xf, false)));
  xi = __float_as_int(x);
  x = fmaxf(x, __int_as_float(__builtin_amdgcn_update_dpp(xi, xi, 0x142, 0xa, 0xf, false)));
  xi = __float_as_int(x);
  x = fmaxf(x, __int_as_float(__builtin_amdgcn_update_dpp(xi, xi, 0x143, 0xc, 0xf, false)));
  return __int_as_float(__builtin_amdgcn_readlane(__float_as_int(x), 63));
}
// lane l <- x from lane l-1; lane 0 <- 0 (DPP wave_shr:1, bound_ctrl) — verified r6
__device__ inline float lane_shr1(float x) {
  return __int_as_float(__builtin_amdgcn_update_dpp(
      0, __float_as_int(x), 0x138, 0xf, 0xf, true));
}

// ---------------- K1: log-softmax + gather -> f32 probs, row per t ----------
// grid (Tc/4, B), block 256: 4 waves, one (b,t) row per wave.
// gw row = 1024B: lane l holds probs of labels 4l..4l+3 (float4). qw = blank.
__global__ __launch_bounds__(256) void k1_gather(
    const float* __restrict__ lp, const int* __restrict__ targets,
    float* __restrict__ gw, float* __restrict__ qw,
    int t0, int T, int Tc, int RB, int Tcp, int S) {
  __shared__ __align__(16) float rowbuf4[4][1024];
  const int w = threadIdx.x >> 6;
  const int lane = threadIdx.x & 63;
  const int tloc = blockIdx.x * 4 + w;
  const int b = blockIdx.y;
  const int t = t0 + tloc;
  const int4 tg4 = *(const int4*)(targets + (size_t)b * S + 4 * lane);
  float* rowbuf = rowbuf4[w];

  const float* row = lp + ((size_t)b * T + t) * 1024;
  const float4 v0 = *(const float4*)(row + 4 * lane);
  const float4 v1 = *(const float4*)(row + 256 + 4 * lane);
  const float4 v2 = *(const float4*)(row + 512 + 4 * lane);
  const float4 v3 = *(const float4*)(row + 768 + 4 * lane);
  float mx = fmaxf(fmaxf(fmaxf(v0.x, v0.y), fmaxf(v0.z, v0.w)),
                   fmaxf(fmaxf(v1.x, v1.y), fmaxf(v1.z, v1.w)));
  mx = fmaxf(mx, fmaxf(fmaxf(fmaxf(v2.x, v2.y), fmaxf(v2.z, v2.w)),
                       fmaxf(fmaxf(v3.x, v3.y), fmaxf(v3.z, v3.w))));
  mx = wave_max64(mx);
  float sm = __expf(v0.x - mx) + __expf(v0.y - mx) + __expf(v0.z - mx) +
             __expf(v0.w - mx) + __expf(v1.x - mx) + __expf(v1.y - mx) +
             __expf(v1.z - mx) + __expf(v1.w - mx) + __expf(v2.x - mx) +
             __expf(v2.y - mx) + __expf(v2.z - mx) + __expf(v2.w - mx) +
             __expf(v3.x - mx) + __expf(v3.y - mx) + __expf(v3.z - mx) +
             __expf(v3.w - mx);
  sm = wave_sum64(sm);
  const float lse = mx + __logf(sm);
  *(float4*)(rowbuf + 4 * lane) = v0;
  *(float4*)(rowbuf + 256 + 4 * lane) = v1;
  *(float4*)(rowbuf + 512 + 4 * lane) = v2;
  *(float4*)(rowbuf + 768 + 4 * lane) = v3;
  const float e0 = __expf(rowbuf[tg4.x] - lse);
  const float e1 = __expf(rowbuf[tg4.y] - lse);
  const float e2 = __expf(rowbuf[tg4.z] - lse);
  const float e3 = __expf(rowbuf[tg4.w] - lse);
  float* gr = gw + ((size_t)b * RB + tloc) * 256;
  *(float4*)(gr + 4 * lane) = make_float4(e0, e1, e2, e3);
  if (lane == 0) qw[(size_t)b * Tcp + tloc] = __expf(rowbuf[0] - lse);
}

// ---------------- K2: alpha recursion, 1 wave/batch, 2-level pipeline -------
// LDS floats: P ring 3*4096 (16 rows/tile) | Q ring @12288 3*64 | fin @12480 513
template <int TSREL>
__global__ __launch_bounds__(64, 1) void k2_alpha(
    const float* __restrict__ gw, const float* __restrict__ qw,
    const int* __restrict__ targets, const int* __restrict__ in_len,
    const int* __restrict__ tgt_len, float* __restrict__ alpha_g,
    int* __restrict__ exp_g, float* __restrict__ tot,
    int t0, int Tc, int RB, int Tcp, int S, int is_last) {
  __shared__ __align__(16) float lds[13000];
  const int b = blockIdx.x;
  const int lane = threadIdx.x;
  const float* gb = gw + (size_t)b * RB * 256;
  const float* qb = qw + (size_t)b * Tcp;
  const int len = in_len[b];
  const int tl = tgt_len[b];
  const int* tg = targets + (size_t)b * S;
  const int4 mytg = *(const int4*)(tg + 4 * lane);
  const int tgm1 = (lane > 0) ? tg[4 * lane - 1] : -1;
  const float sk1 = (lane > 0 && mytg.x != tgm1) ? 1.f : 0.f;
  const float sk3 = (mytg.y != mytg.x) ? 1.f : 0.f;
  const float sk5 = (mytg.z != mytg.y) ? 1.f : 0.f;
  const float sk7 = (mytg.w != mytg.z) ? 1.f : 0.f;

  float a0 = 0.f, a1 = 0.f, a2 = 0.f, a3 = 0.f, a4 = 0.f, a5 = 0.f, a6 = 0.f,
        a7 = 0.f, a8 = 0.f;
  int E = 0;
  if (TSREL) {
    if (lane == 0) { a0 = qb[0]; a1 = gb[0]; }
  } else {
    const float* ap = alpha_g + (size_t)b * 520 + 8 * lane;
    a0 = ap[0]; a1 = ap[1]; a2 = ap[2]; a3 = ap[3];
    a4 = ap[4]; a5 = ap[5]; a6 = ap[6]; a7 = ap[7];
    a8 = (lane == 63) ? alpha_g[(size_t)b * 520 + 512] : 0.f;
    E = exp_g[b];
  }

  const int t_hi = min(t0 + Tc, len);
  int N = t_hi - (t0 + TSREL);
  if (N < 0) N = 0;
  const int NT = (N + 15) >> 4;

  auto dma = [&](int j) {  // stage tile j (16 rows + 64 blank probs)
    const int s = j - (j / 3) * 3;
    const int r0 = TSREL + 16 * j;
    const float* src = gb + (size_t)r0 * 256 + 4 * lane;
    float* dp = lds + s * 4096;
#pragma unroll
    for (int r = 0; r < 16; ++r) GLL16(src + r * 256, dp + r * 256);
    GLL4(qb + r0 + lane, lds + 12288 + s * 64);
  };

#define DECLSET(X) float4 X##0, X##1, X##2, X##3, X##4, X##5, X##6, X##7, X##qA, X##qB;
  DECLSET(A)
  DECLSET(B)

#define LOADSET(X, jj, h)                                                   \
  {                                                                         \
    const int s_ = (jj) - ((jj) / 3) * 3;                                   \
    const float* sp_ = lds + s_ * 4096 + (h)*2048 + 4 * lane;               \
    X##0 = *(const float4*)(sp_);                                           \
    X##1 = *(const float4*)(sp_ + 256);                                     \
    X##2 = *(const float4*)(sp_ + 512);                                     \
    X##3 = *(const float4*)(sp_ + 768);                                     \
    X##4 = *(const float4*)(sp_ + 1024);                                    \
    X##5 = *(const float4*)(sp_ + 1280);                                    \
    X##6 = *(const float4*)(sp_ + 1536);                                    \
    X##7 = *(const float4*)(sp_ + 1792);                                    \
    const float* qp_ = lds + 12288 + s_ * 64 + (h)*8;                       \
    X##qA = *(const float4*)(qp_);                                          \
    X##qB = *(const float4*)(qp_ + 4);                                      \
  }

#define KSR(pv, qv)                                              \
  {                                                              \
    const float hm1 = lane_shr1(a7);                             \
    const float n0 = (a0 + hm1) * (qv);                          \
    const float n1 = __fmaf_rn(sk1, hm1, a1 + a0) * (pv).x;      \
    const float n2 = (a2 + a1) * (qv);                           \
    const float n3 = __fmaf_rn(sk3, a1, a3 + a2) * (pv).y;       \
    const float n4 = (a4 + a3) * (qv);                           \
    const float n5 = __fmaf_rn(sk5, a3, a5 + a4) * (pv).z;       \
    const float n6 = (a6 + a5) * (qv);                           \
    const float n7 = __fmaf_rn(sk7, a5, a7 + a6) * (pv).w;       \
    const float n8 = (a8 + a7) * (qv);                           \
    a0 = n0; a1 = n1; a2 = n2; a3 = n3; a4 = n4;                 \
    a5 = n5; a6 = n6; a7 = n7; a8 = n8;                          \
  }

#define RESC()                                                            \
  {                                                                       \
    float m_ = fmaxf(fmaxf(fmaxf(fmaxf(a0, a1), fmaxf(a2, a3)),           \
                           fmaxf(fmaxf(a4, a5), fmaxf(a6, a7))), a8);     \
    m_ = wave_max_dpp(m_);                                                \
    const int e_ =                                                        \
        (m_ > 0.f) ? (int)((__float_as_uint(m_) >> 23) & 255u) - 127 : 0; \
    a0 = ldexpf(a0, -e_); a1 = ldexpf(a1, -e_); a2 = ldexpf(a2, -e_);     \
    a3 = ldexpf(a3, -e_); a4 = ldexpf(a4, -e_); a5 = ldexpf(a5, -e_);     \
    a6 = ldexpf(a6, -e_); a7 = ldexpf(a7, -e_); a8 = ldexpf(a8, -e_);     \
    E += e_;                                                              \
  }

#define COMP8F(X)                                  \
  KSR(X##0, X##qA.x) KSR(X##1, X##qA.y)            \
  KSR(X##2, X##qA.z) KSR(X##3, X##qA.w)            \
  KSR(X##4, X##qB.x) KSR(X##5, X##qB.y)            \
  KSR(X##6, X##qB.z) KSR(X##7, X##qB.w) RESC()

#define COMP8G(X, base, rem)                          \
  {                                                   \
    if ((rem) > (base) + 0) KSR(X##0, X##qA.x)        \
    if ((rem) > (base) + 1) KSR(X##1, X##qA.y)        \
    if ((rem) > (base) + 2) KSR(X##2, X##qA.z)        \
    if ((rem) > (base) + 3) KSR(X##3, X##qA.w)        \
    if ((rem) > (base) + 4) KSR(X##4, X##qB.x)        \
    if ((rem) > (base) + 5) KSR(X##5, X##qB.y)        \
    if ((rem) > (base) + 6) KSR(X##6, X##qB.z)        \
    if ((rem) > (base) + 7) KSR(X##7, X##qB.w)        \
    RESC()                                            \
  }

  if (NT > 0) dma(0);
  if (NT > 1) dma(1);
  if (NT > 2) dma(2);
  if (NT > 2) {
    asm volatile("s_waitcnt vmcnt(34)" ::: "memory");
  } else if (NT > 1) {
    asm volatile("s_waitcnt vmcnt(17)" ::: "memory");
  } else {
    asm volatile("s_waitcnt vmcnt(0)" ::: "memory");
  }
  SB();
  if (NT > 0) LOADSET(A, 0, 0);
  SB();

  for (int j = 0; j < NT; ++j) {
    const int rem = N - 16 * j;
    // ---- h0: issue B's reads (steps 8..15), compute A (steps 0..7) ----
    LOADSET(B, j, 1);
    SB();
    if (rem >= 8) { COMP8F(A) } else { COMP8G(A, 0, rem) }
    SB();
    // ---- h1: ring maintenance + issue A's reads for next tile, compute B ----
    asm volatile("s_waitcnt lgkmcnt(0)" ::: "memory");  // slot j%3 reads done
    SB();
    if (j + 1 < NT) {
      if (j + 2 < NT) {
        asm volatile("s_waitcnt vmcnt(17)" ::: "memory");  // tile j+1 staged
      } else {
        asm volatile("s_waitcnt vmcnt(0)" ::: "memory");
      }
      SB();
      if (j + 3 < NT) dma(j + 3);
      LOADSET(A, j + 1, 0);
    }
    SB();
    if (rem >= 16) { COMP8F(B) }
    else if (rem > 8) { COMP8G(B, 8, rem) }
    else { RESC() }
    SB();
  }
#undef COMP8F
#undef COMP8G
#undef KSR
#undef RESC
#undef LOADSET
#undef DECLSET

  if (is_last) {
    float* fin = lds + 12480;
    fin[8 * lane + 0] = a0; fin[8 * lane + 1] = a1;
    fin[8 * lane + 2] = a2; fin[8 * lane + 3] = a3;
    fin[8 * lane + 4] = a4; fin[8 * lane + 5] = a5;
    fin[8 * lane + 6] = a6; fin[8 * lane + 7] = a7;
    if (lane == 63) fin[512] = a8;
    asm volatile("s_waitcnt lgkmcnt(0)" ::: "memory");
    SB();
    if (lane == 0) {
      const int i1 = 2 * tl;
      const int i2 = (2 * tl - 1 > 0) ? (2 * tl - 1) : 0;
      float v = fin[i1] + ((tl > 0) ? fin[i2] : 0.f);
      v = fmaxf(v, 1e-37f);
      tot[b] = logf(v) + (float)E * 0.6931471805599453f;
    }
  } else {
    float* ap = alpha_g + (size_t)b * 520 + 8 * lane;
    ap[0] = a0; ap[1] = a1; ap[2] = a2; ap[3] = a3;
    ap[4] = a4; ap[5] = a5; ap[6] = a6; ap[7] = a7;
    if (lane == 63) alpha_g[(size_t)b * 520 + 512] = a8;
    if (lane == 0) exp_g[b] = E;
  }
}

// ---------------- K3: -mean over batch ----------------
__global__ void k3_mean(const float* __restrict__ tot, float* __restrict__ out,
                        int B) {
  float v = (threadIdx.x < B) ? tot[threadIdx.x] : 0.0f;
  v = wave_sum64(v);
  if (threadIdx.x == 0) out[0] = -v / (float)B;
}

// ---------------- host ----------------
extern "C" void kernel_launch(void* const* d_in, const int* in_sizes, int n_in,
                              void* d_out, int out_size, void* d_ws,
                              size_t ws_size, hipStream_t stream) {
  const float* lp = (const float*)d_in[0];
  const int* targets = (const int*)d_in[1];
  const int* in_len = (const int*)d_in[2];
  const int* tgt_len = (const int*)d_in[3];
  float* out = (float*)d_out;

  const int B = in_sizes[2];               // 64
  const int S = in_sizes[1] / B;           // 256
  const int C = 1024;
  const int T = (int)((size_t)in_sizes[0] / ((size_t)B * C));  // 2048

  const size_t headf = 64 + 64 + (size_t)64 * 520;  // tot | exp_g | alpha_g
  int Tc = T, RB = 0, Tcp = 0;
  for (;;) {
    RB = Tc + 32;   // rows per batch incl. DMA over-read pad
    Tcp = Tc + 96;  // blank rows incl. over-read pad
    const size_t need =
        headf * 4 + (size_t)64 * Tcp * 4 + (size_t)64 * RB * 1024;
    if (need <= ws_size || Tc <= 64) break;
    Tc >>= 1;
  }

  float* tot = (float*)d_ws;
  int* exp_g = (int*)(tot + 64);
  float* alpha_g = (float*)(exp_g + 64);
  float* qw = alpha_g + (size_t)64 * 520;
  float* gw = qw + (size_t)64 * Tcp;

  const int nch = (T + Tc - 1) / Tc;
  for (int c = 0; c < nch; ++c) {
    const int t0 = c * Tc;
    k1_gather<<<dim3(Tc / 4, B), 256, 0, stream>>>(lp, targets, gw, qw, t0, T,
                                                   Tc, RB, Tcp, S);
    const int last = (c == nch - 1) ? 1 : 0;
    if (c == 0)
      k2_alpha<1><<<B, 64, 0, stream>>>(gw, qw, targets, in_len, tgt_len,
                                        alpha_g, exp_g, tot, t0, Tc, RB, Tcp,
                                        S, last);
    else
      k2_alpha<0><<<B, 64, 0, stream>>>(gw, qw, targets, in_len, tgt_len,
                                        alpha_g, exp_g, tot, t0, Tc, RB, Tcp,
                                        S, last);
  }
  k3_mean<<<1, 64, 0, stream>>>(tot, out, B);
}

// Round 11
// 265.856 us; speedup vs baseline: 1.3249x; 1.3249x over previous
//
#include <hip/hip_runtime.h>
#include <math.h>

typedef __attribute__((ext_vector_type(4))) float f32x4;

#define SB() __builtin_amdgcn_sched_barrier(0)
#define WAITV(n)                                              \
  do {                                                        \
    asm volatile("s_waitcnt vmcnt(" #n ")" ::: "memory");     \
    SB();                                                     \
  } while (0)
// inline-asm loads: invisible to SIInsertWaitcnts -> no compiler vmcnt(0) drains
// NOTE: offset: is 13-bit SIGNED (<=4095) -> keep immediates in {0..3168}
#define LD4(dst, ptr, OFF)                                           \
  asm volatile("global_load_dwordx4 %0, %1, off offset:" OFF         \
               : "=v"(dst) : "v"(ptr) : "memory")
#define LD1(dst, ptr, OFF)                                           \
  asm volatile("global_load_dword %0, %1, off offset:" OFF           \
               : "=v"(dst) : "v"(ptr) : "memory")

__device__ inline float wave_max64(float v) {
#pragma unroll
  for (int off = 32; off > 0; off >>= 1) v = fmaxf(v, __shfl_xor(v, off, 64));
  return v;
}
__device__ inline float wave_sum64(float v) {
#pragma unroll
  for (int off = 32; off > 0; off >>= 1) v += __shfl_xor(v, off, 64);
  return v;
}
// wave64 max via DPP, broadcast via readlane63 (verified r4-r7)
__device__ inline float wave_max_dpp(float x) {
  int xi = __float_as_int(x);
  x = fmaxf(x, __int_as_float(__builtin_amdgcn_update_dpp(xi, xi, 0x111, 0xf, 0xf, false)));
  xi = __float_as_int(x);
  x = fmaxf(x, __int_as_float(__builtin_amdgcn_update_dpp(xi, xi, 0x112, 0xf, 0xf, false)));
  xi = __float_as_int(x);
  x = fmaxf(x, __int_as_float(__builtin_amdgcn_update_dpp(xi, xi, 0x114, 0xf, 0xf, false)));
  xi = __float_as_int(x);
  x = fmaxf(x, __int_as_float(__builtin_amdgcn_update_dpp(xi, xi, 0x118, 0xf, 0xf, false)));
  xi = __float_as_int(x);
  x = fmaxf(x, __int_as_float(__builtin_amdgcn_update_dpp(xi, xi, 0x142, 0xa, 0xf, false)));
  xi = __float_as_int(x);
  x = fmaxf(x, __int_as_float(__builtin_amdgcn_update_dpp(xi, xi, 0x143, 0xc, 0xf, false)));
  return __int_as_float(__builtin_amdgcn_readlane(__float_as_int(x), 63));
}
// lane l <- x from lane l-1; lane 0 <- 0 (DPP wave_shr:1, verified r6-r7)
__device__ inline float lane_shr1(float x) {
  return __int_as_float(__builtin_amdgcn_update_dpp(
      0, __float_as_int(x), 0x138, 0xf, 0xf, true));
}

// ---------------- K1: log-softmax + gather -> packed f32 rows ----------------
// grid (Tc/4, B), block 256: one (b,t) row per wave.
// Row record = 264 floats (1056 B): [0..255] target probs, [256] blank, pad.
__global__ __launch_bounds__(256) void k1_gather(
    const float* __restrict__ lp, const int* __restrict__ targets,
    float* __restrict__ gw, int t0, int T, int Tc, int RB, int S) {
  __shared__ __align__(16) float rowbuf4[4][1024];
  const int w = threadIdx.x >> 6;
  const int lane = threadIdx.x & 63;
  const int tloc = blockIdx.x * 4 + w;
  const int b = blockIdx.y;
  const int t = t0 + tloc;
  const int4 tg4 = *(const int4*)(targets + (size_t)b * S + 4 * lane);
  float* rowbuf = rowbuf4[w];

  const float* row = lp + ((size_t)b * T + t) * 1024;
  const float4 v0 = *(const float4*)(row + 4 * lane);
  const float4 v1 = *(const float4*)(row + 256 + 4 * lane);
  const float4 v2 = *(const float4*)(row + 512 + 4 * lane);
  const float4 v3 = *(const float4*)(row + 768 + 4 * lane);
  float mx = fmaxf(fmaxf(fmaxf(v0.x, v0.y), fmaxf(v0.z, v0.w)),
                   fmaxf(fmaxf(v1.x, v1.y), fmaxf(v1.z, v1.w)));
  mx = fmaxf(mx, fmaxf(fmaxf(fmaxf(v2.x, v2.y), fmaxf(v2.z, v2.w)),
                       fmaxf(fmaxf(v3.x, v3.y), fmaxf(v3.z, v3.w))));
  mx = wave_max64(mx);
  float sm = __expf(v0.x - mx) + __expf(v0.y - mx) + __expf(v0.z - mx) +
             __expf(v0.w - mx) + __expf(v1.x - mx) + __expf(v1.y - mx) +
             __expf(v1.z - mx) + __expf(v1.w - mx) + __expf(v2.x - mx) +
             __expf(v2.y - mx) + __expf(v2.z - mx) + __expf(v2.w - mx) +
             __expf(v3.x - mx) + __expf(v3.y - mx) + __expf(v3.z - mx) +
             __expf(v3.w - mx);
  sm = wave_sum64(sm);
  const float lse = mx + __logf(sm);
  *(float4*)(rowbuf + 4 * lane) = v0;
  *(float4*)(rowbuf + 256 + 4 * lane) = v1;
  *(float4*)(rowbuf + 512 + 4 * lane) = v2;
  *(float4*)(rowbuf + 768 + 4 * lane) = v3;
  const float e0 = __expf(rowbuf[tg4.x] - lse);
  const float e1 = __expf(rowbuf[tg4.y] - lse);
  const float e2 = __expf(rowbuf[tg4.z] - lse);
  const float e3 = __expf(rowbuf[tg4.w] - lse);
  float* gr = gw + ((size_t)b * RB + tloc) * 264;
  *(float4*)(gr + 4 * lane) = make_float4(e0, e1, e2, e3);
  if (lane == 0) gr[256] = __expf(rowbuf[0] - lse);
}

// ---------------- K2: alpha recursion, 1 wave/batch, asm-reg pipeline -------
#define DECL8(P)                                                     \
  f32x4 P##v0, P##v1, P##v2, P##v3, P##v4, P##v5, P##v6, P##v7;      \
  float P##q0, P##q1, P##q2, P##q3, P##q4, P##q5, P##q6, P##q7;

// two bases 4 rows apart keep all immediates <= 3168 (13-bit signed limit)
#define ISS8(P)                                                      \
  do {                                                               \
    LD4(P##v0, gpA_, "0");    LD1(P##q0, gqA_, "0");                 \
    LD4(P##v1, gpA_, "1056"); LD1(P##q1, gqA_, "1056");              \
    LD4(P##v2, gpA_, "2112"); LD1(P##q2, gqA_, "2112");              \
    LD4(P##v3, gpA_, "3168"); LD1(P##q3, gqA_, "3168");              \
    LD4(P##v4, gpB_, "0");    LD1(P##q4, gqB_, "0");                 \
    LD4(P##v5, gpB_, "1056"); LD1(P##q5, gqB_, "1056");              \
    LD4(P##v6, gpB_, "2112"); LD1(P##q6, gqB_, "2112");              \
    LD4(P##v7, gpB_, "3168"); LD1(P##q7, gqB_, "3168");              \
    gpA_ += 2112; gqA_ += 2112; gpB_ += 2112; gqB_ += 2112;          \
  } while (0)

#define KSR(pv, qv)                                              \
  {                                                              \
    const float hm1 = lane_shr1(a7);                             \
    const float n0 = (a0 + hm1) * (qv);                          \
    const float n1 = __fmaf_rn(sk1, hm1, a1 + a0) * (pv).x;      \
    const float n2 = (a2 + a1) * (qv);                           \
    const float n3 = __fmaf_rn(sk3, a1, a3 + a2) * (pv).y;       \
    const float n4 = (a4 + a3) * (qv);                           \
    const float n5 = __fmaf_rn(sk5, a3, a5 + a4) * (pv).z;       \
    const float n6 = (a6 + a5) * (qv);                           \
    const float n7 = __fmaf_rn(sk7, a5, a7 + a6) * (pv).w;       \
    const float n8 = (a8 + a7) * (qv);                           \
    a0 = n0; a1 = n1; a2 = n2; a3 = n3; a4 = n4;                 \
    a5 = n5; a6 = n6; a7 = n7; a8 = n8;                          \
  }

#define RESC()                                                            \
  {                                                                       \
    float m_ = fmaxf(fmaxf(fmaxf(fmaxf(a0, a1), fmaxf(a2, a3)),           \
                           fmaxf(fmaxf(a4, a5), fmaxf(a6, a7))), a8);     \
    m_ = wave_max_dpp(m_);                                                \
    const int e_ =                                                        \
        (m_ > 0.f) ? (int)((__float_as_uint(m_) >> 23) & 255u) - 127 : 0; \
    a0 = ldexpf(a0, -e_); a1 = ldexpf(a1, -e_); a2 = ldexpf(a2, -e_);     \
    a3 = ldexpf(a3, -e_); a4 = ldexpf(a4, -e_); a5 = ldexpf(a5, -e_);     \
    a6 = ldexpf(a6, -e_); a7 = ldexpf(a7, -e_); a8 = ldexpf(a8, -e_);     \
    E += e_;                                                              \
  }

#define COMP8(P, rem)                                            \
  do {                                                           \
    if ((rem) >= 8) {                                            \
      KSR(P##v0, P##q0) KSR(P##v1, P##q1) KSR(P##v2, P##q2)      \
      KSR(P##v3, P##q3) KSR(P##v4, P##q4) KSR(P##v5, P##q5)      \
      KSR(P##v6, P##q6) KSR(P##v7, P##q7) RESC()                 \
    } else {                                                     \
      KSR(P##v0, P##q0)                                          \
      if ((rem) > 1) KSR(P##v1, P##q1)                           \
      if ((rem) > 2) KSR(P##v2, P##q2)                           \
      if ((rem) > 3) KSR(P##v3, P##q3)                           \
      if ((rem) > 4) KSR(P##v4, P##q4)                           \
      if ((rem) > 5) KSR(P##v5, P##q5)                           \
      if ((rem) > 6) KSR(P##v6, P##q6)                           \
      RESC()                                                     \
    }                                                            \
  } while (0)

template <int TSREL>
__global__ __launch_bounds__(64, 1) void k2_alpha(
    const float* __restrict__ gw, const int* __restrict__ targets,
    const int* __restrict__ in_len, const int* __restrict__ tgt_len,
    float* __restrict__ alpha_g, int* __restrict__ exp_g,
    float* __restrict__ tot, int t0, int Tc, int RB, int S, int is_last) {
  __shared__ float fin[520];
  const int b = blockIdx.x;
  const int lane = threadIdx.x;
  const float* gb = gw + (size_t)b * RB * 264;
  const int len = in_len[b];
  const int tl = tgt_len[b];
  const int* tg = targets + (size_t)b * S;
  const int4 mytg = *(const int4*)(tg + 4 * lane);
  const int tgm1 = (lane > 0) ? tg[4 * lane - 1] : -1;
  const float sk1 = (lane > 0 && mytg.x != tgm1) ? 1.f : 0.f;
  const float sk3 = (mytg.y != mytg.x) ? 1.f : 0.f;
  const float sk5 = (mytg.z != mytg.y) ? 1.f : 0.f;
  const float sk7 = (mytg.w != mytg.z) ? 1.f : 0.f;

  float a0 = 0.f, a1 = 0.f, a2 = 0.f, a3 = 0.f, a4 = 0.f, a5 = 0.f, a6 = 0.f,
        a7 = 0.f, a8 = 0.f;
  int E = 0;
  if (TSREL) {
    if (lane == 0) { a0 = gb[256]; a1 = gb[0]; }  // t=0: blank, first label
  } else {
    const float* ap = alpha_g + (size_t)b * 520 + 8 * lane;
    a0 = ap[0]; a1 = ap[1]; a2 = ap[2]; a3 = ap[3];
    a4 = ap[4]; a5 = ap[5]; a6 = ap[6]; a7 = ap[7];
    a8 = (lane == 63) ? alpha_g[(size_t)b * 520 + 512] : 0.f;
    E = exp_g[b];
  }

  const int t_hi = min(t0 + Tc, len);
  int N = t_hi - (t0 + TSREL);
  if (N < 0) N = 0;
  const int G = (N + 7) >> 3;  // 8-step groups

  const float* gpA_ = gb + (size_t)TSREL * 264 + 4 * lane;
  const float* gqA_ = gb + (size_t)TSREL * 264 + 256;
  const float* gpB_ = gpA_ + 1056;  // 4 rows ahead
  const float* gqB_ = gqA_ + 1056;

  DECL8(A) DECL8(B) DECL8(C)

  // drain compiler-tracked loads so our manual vmcnt counting starts at 0
  asm volatile("s_waitcnt vmcnt(0) lgkmcnt(0)" ::: "memory");
  SB();
  ISS8(A); ISS8(B); ISS8(C);  // 48 vmem ops in flight (24-step prefetch)

  for (int g = 0; g < G; g += 3) {
    WAITV(32);                       // set A resident
    COMP8(A, N - 8 * g);
    ISS8(A);
    if (g + 1 < G) {
      WAITV(32);                     // set B resident
      COMP8(B, N - 8 * (g + 1));
      ISS8(B);
    }
    if (g + 2 < G) {
      WAITV(32);                     // set C resident
      COMP8(C, N - 8 * (g + 2));
      ISS8(C);
    }
  }
  WAITV(0);  // retire stragglers before epilogue

  if (is_last) {
    fin[8 * lane + 0] = a0; fin[8 * lane + 1] = a1;
    fin[8 * lane + 2] = a2; fin[8 * lane + 3] = a3;
    fin[8 * lane + 4] = a4; fin[8 * lane + 5] = a5;
    fin[8 * lane + 6] = a6; fin[8 * lane + 7] = a7;
    if (lane == 63) fin[512] = a8;
    asm volatile("s_waitcnt lgkmcnt(0)" ::: "memory");
    SB();
    if (lane == 0) {
      const int i1 = 2 * tl;
      const int i2 = (2 * tl - 1 > 0) ? (2 * tl - 1) : 0;
      float v = fin[i1] + ((tl > 0) ? fin[i2] : 0.f);
      v = fmaxf(v, 1e-37f);
      tot[b] = logf(v) + (float)E * 0.6931471805599453f;
    }
  } else {
    float* ap = alpha_g + (size_t)b * 520 + 8 * lane;
    ap[0] = a0; ap[1] = a1; ap[2] = a2; ap[3] = a3;
    ap[4] = a4; ap[5] = a5; ap[6] = a6; ap[7] = a7;
    if (lane == 63) alpha_g[(size_t)b * 520 + 512] = a8;
    if (lane == 0) exp_g[b] = E;
  }
}

// ---------------- K3: -mean over batch ----------------
__global__ void k3_mean(const float* __restrict__ tot, float* __restrict__ out,
                        int B) {
  float v = (threadIdx.x < B) ? tot[threadIdx.x] : 0.0f;
  v = wave_sum64(v);
  if (threadIdx.x == 0) out[0] = -v / (float)B;
}

// ---------------- host ----------------
extern "C" void kernel_launch(void* const* d_in, const int* in_sizes, int n_in,
                              void* d_out, int out_size, void* d_ws,
                              size_t ws_size, hipStream_t stream) {
  const float* lp = (const float*)d_in[0];
  const int* targets = (const int*)d_in[1];
  const int* in_len = (const int*)d_in[2];
  const int* tgt_len = (const int*)d_in[3];
  float* out = (float*)d_out;

  const int B = in_sizes[2];               // 64
  const int S = in_sizes[1] / B;           // 256
  const int C = 1024;
  const int T = (int)((size_t)in_sizes[0] / ((size_t)B * C));  // 2048

  const size_t headf = 64 + 64 + (size_t)64 * 520;  // tot | exp_g | alpha_g
  int Tc = T, RB = 0;
  for (;;) {
    RB = Tc + 56;  // pad rows cover 24-step prefetch over-read
    const size_t need = headf * 4 + (size_t)64 * RB * 1056;
    if (need <= ws_size || Tc <= 64) break;
    Tc >>= 1;
  }

  float* tot = (float*)d_ws;
  int* exp_g = (int*)(tot + 64);
  float* alpha_g = (float*)(exp_g + 64);
  float* gw = alpha_g + (size_t)64 * 520;

  const int nch = (T + Tc - 1) / Tc;
  for (int c = 0; c < nch; ++c) {
    const int t0 = c * Tc;
    k1_gather<<<dim3(Tc / 4, B), 256, 0, stream>>>(lp, targets, gw, t0, T, Tc,
                                                   RB, S);
    const int last = (c == nch - 1) ? 1 : 0;
    if (c == 0)
      k2_alpha<1><<<B, 64, 0, stream>>>(gw, targets, in_len, tgt_len, alpha_g,
                                        exp_g, tot, t0, Tc, RB, S, last);
    else
      k2_alpha<0><<<B, 64, 0, stream>>>(gw, targets, in_len, tgt_len, alpha_g,
                                        exp_g, tot, t0, Tc, RB, S, last);
  }
  k3_mean<<<1, 64, 0, stream>>>(tot, out, B);
}

// Round 12
// 234.208 us; speedup vs baseline: 1.5040x; 1.1351x over previous
//
#include <hip/hip_runtime.h>
#include <math.h>

typedef __attribute__((ext_vector_type(4))) float f32x4;

#define SB() __builtin_amdgcn_sched_barrier(0)
#define WAITV(n)                                              \
  do {                                                        \
    asm volatile("s_waitcnt vmcnt(" #n ")" ::: "memory");     \
    SB();                                                     \
  } while (0)
// inline-asm loads: invisible to SIInsertWaitcnts (no compiler vmcnt(0) drains)
// offset: is 13-bit signed -> immediates kept in {0,1088,2176,3264}
#define LD4(dst, ptr, OFF)                                           \
  asm volatile("global_load_dwordx4 %0, %1, off offset:" OFF         \
               : "=v"(dst) : "v"(ptr) : "memory")
#define LD1(dst, ptr, OFF)                                           \
  asm volatile("global_load_dword %0, %1, off offset:" OFF           \
               : "=v"(dst) : "v"(ptr) : "memory")

__device__ inline float wave_max64(float v) {
#pragma unroll
  for (int off = 32; off > 0; off >>= 1) v = fmaxf(v, __shfl_xor(v, off, 64));
  return v;
}
__device__ inline float wave_sum64(float v) {
#pragma unroll
  for (int off = 32; off > 0; off >>= 1) v += __shfl_xor(v, off, 64);
  return v;
}
// wave64 max via DPP, broadcast via readlane63 (verified r4-r11)
__device__ inline float wave_max_dpp(float x) {
  int xi = __float_as_int(x);
  x = fmaxf(x, __int_as_float(__builtin_amdgcn_update_dpp(xi, xi, 0x111, 0xf, 0xf, false)));
  xi = __float_as_int(x);
  x = fmaxf(x, __int_as_float(__builtin_amdgcn_update_dpp(xi, xi, 0x112, 0xf, 0xf, false)));
  xi = __float_as_int(x);
  x = fmaxf(x, __int_as_float(__builtin_amdgcn_update_dpp(xi, xi, 0x114, 0xf, 0xf, false)));
  xi = __float_as_int(x);
  x = fmaxf(x, __int_as_float(__builtin_amdgcn_update_dpp(xi, xi, 0x118, 0xf, 0xf, false)));
  xi = __float_as_int(x);
  x = fmaxf(x, __int_as_float(__builtin_amdgcn_update_dpp(xi, xi, 0x142, 0xa, 0xf, false)));
  xi = __float_as_int(x);
  x = fmaxf(x, __int_as_float(__builtin_amdgcn_update_dpp(xi, xi, 0x143, 0xc, 0xf, false)));
  return __int_as_float(__builtin_amdgcn_readlane(__float_as_int(x), 63));
}
// lane l <- x from lane l-1; lane 0 <- 0 (DPP wave_shr:1, verified r6-r11)
__device__ inline float lane_shr1(float x) {
  return __int_as_float(__builtin_amdgcn_update_dpp(
      0, __float_as_int(x), 0x138, 0xf, 0xf, true));
}

// ---------------- k1 body: log-softmax + gather -> packed f32 rows ----------
// Chunk-local row record = 272 floats (1088 B): [0..255] target probs,
// [256] blank, pad. One (b,t) row per wave.
__device__ __forceinline__ void k1_body(
    const float* __restrict__ lp, const int* __restrict__ targets,
    float* __restrict__ gw, int t0, int T, int Tc, int CB, int S,
    int b, int tq, float* rowbuf) {
  const int lane = threadIdx.x & 63;
  const int w = threadIdx.x >> 6;
  const int tloc = tq * 4 + w;
  const int t = t0 + tloc;
  if (t >= T) return;
  const int4 tg4 = *(const int4*)(targets + (size_t)b * S + 4 * lane);

  const float* row = lp + ((size_t)b * T + t) * 1024;
  const float4 v0 = *(const float4*)(row + 4 * lane);
  const float4 v1 = *(const float4*)(row + 256 + 4 * lane);
  const float4 v2 = *(const float4*)(row + 512 + 4 * lane);
  const float4 v3 = *(const float4*)(row + 768 + 4 * lane);
  float mx = fmaxf(fmaxf(fmaxf(v0.x, v0.y), fmaxf(v0.z, v0.w)),
                   fmaxf(fmaxf(v1.x, v1.y), fmaxf(v1.z, v1.w)));
  mx = fmaxf(mx, fmaxf(fmaxf(fmaxf(v2.x, v2.y), fmaxf(v2.z, v2.w)),
                       fmaxf(fmaxf(v3.x, v3.y), fmaxf(v3.z, v3.w))));
  mx = wave_max64(mx);
  float sm = __expf(v0.x - mx) + __expf(v0.y - mx) + __expf(v0.z - mx) +
             __expf(v0.w - mx) + __expf(v1.x - mx) + __expf(v1.y - mx) +
             __expf(v1.z - mx) + __expf(v1.w - mx) + __expf(v2.x - mx) +
             __expf(v2.y - mx) + __expf(v2.z - mx) + __expf(v2.w - mx) +
             __expf(v3.x - mx) + __expf(v3.y - mx) + __expf(v3.z - mx) +
             __expf(v3.w - mx);
  sm = wave_sum64(sm);
  const float lse = mx + __logf(sm);
  *(float4*)(rowbuf + 4 * lane) = v0;
  *(float4*)(rowbuf + 256 + 4 * lane) = v1;
  *(float4*)(rowbuf + 512 + 4 * lane) = v2;
  *(float4*)(rowbuf + 768 + 4 * lane) = v3;
  const float e0 = __expf(rowbuf[tg4.x] - lse);
  const float e1 = __expf(rowbuf[tg4.y] - lse);
  const float e2 = __expf(rowbuf[tg4.z] - lse);
  const float e3 = __expf(rowbuf[tg4.w] - lse);
  float* gr = gw + ((size_t)b * CB + tloc) * 272;
  *(float4*)(gr + 4 * lane) = make_float4(e0, e1, e2, e3);
  if (lane == 0) gr[256] = __expf(rowbuf[0] - lse);
}

__global__ __launch_bounds__(256) void k1_std(
    const float* __restrict__ lp, const int* __restrict__ targets,
    float* __restrict__ gw, int t0, int T, int Tc, int CB, int S) {
  __shared__ __align__(16) float rowbuf4[4][1024];
  k1_body(lp, targets, gw, t0, T, Tc, CB, S, blockIdx.y, blockIdx.x,
          rowbuf4[threadIdx.x >> 6]);
}

// ---------------- k2 body: alpha recursion, 1 wave/batch, 2-set asm pipe ----
#define DECL8(P)                                                     \
  f32x4 P##v0, P##v1, P##v2, P##v3, P##v4, P##v5, P##v6, P##v7;      \
  float P##q0, P##q1, P##q2, P##q3, P##q4, P##q5, P##q6, P##q7;

// two bases 4 rows (4*272 floats = 4352 B) apart; row stride 1088 B
#define ISS8(P)                                                      \
  do {                                                               \
    LD4(P##v0, gpA_, "0");    LD1(P##q0, gqA_, "0");                 \
    LD4(P##v1, gpA_, "1088"); LD1(P##q1, gqA_, "1088");              \
    LD4(P##v2, gpA_, "2176"); LD1(P##q2, gqA_, "2176");              \
    LD4(P##v3, gpA_, "3264"); LD1(P##q3, gqA_, "3264");              \
    LD4(P##v4, gpB_, "0");    LD1(P##q4, gqB_, "0");                 \
    LD4(P##v5, gpB_, "1088"); LD1(P##q5, gqB_, "1088");              \
    LD4(P##v6, gpB_, "2176"); LD1(P##q6, gqB_, "2176");              \
    LD4(P##v7, gpB_, "3264"); LD1(P##q7, gqB_, "3264");              \
    gpA_ += 2176; gqA_ += 2176; gpB_ += 2176; gqB_ += 2176;          \
  } while (0)

#define KSR(pv, qv)                                              \
  {                                                              \
    const float hm1 = lane_shr1(a7);                             \
    const float n0 = (a0 + hm1) * (qv);                          \
    const float n1 = __fmaf_rn(sk1, hm1, a1 + a0) * (pv).x;      \
    const float n2 = (a2 + a1) * (qv);                           \
    const float n3 = __fmaf_rn(sk3, a1, a3 + a2) * (pv).y;       \
    const float n4 = (a4 + a3) * (qv);                           \
    const float n5 = __fmaf_rn(sk5, a3, a5 + a4) * (pv).z;       \
    const float n6 = (a6 + a5) * (qv);                           \
    const float n7 = __fmaf_rn(sk7, a5, a7 + a6) * (pv).w;       \
    const float n8 = (a8 + a7) * (qv);                           \
    a0 = n0; a1 = n1; a2 = n2; a3 = n3; a4 = n4;                 \
    a5 = n5; a6 = n6; a7 = n7; a8 = n8;                          \
  }

#define RESC()                                                            \
  {                                                                       \
    float m_ = fmaxf(fmaxf(fmaxf(fmaxf(a0, a1), fmaxf(a2, a3)),           \
                           fmaxf(fmaxf(a4, a5), fmaxf(a6, a7))), a8);     \
    m_ = wave_max_dpp(m_);                                                \
    const int e_ =                                                        \
        (m_ > 0.f) ? (int)((__float_as_uint(m_) >> 23) & 255u) - 127 : 0; \
    a0 = ldexpf(a0, -e_); a1 = ldexpf(a1, -e_); a2 = ldexpf(a2, -e_);     \
    a3 = ldexpf(a3, -e_); a4 = ldexpf(a4, -e_); a5 = ldexpf(a5, -e_);     \
    a6 = ldexpf(a6, -e_); a7 = ldexpf(a7, -e_); a8 = ldexpf(a8, -e_);     \
    E += e_;                                                              \
  }

#define COMP8(P, rem)                                            \
  do {                                                           \
    if ((rem) >= 8) {                                            \
      KSR(P##v0, P##q0) KSR(P##v1, P##q1) KSR(P##v2, P##q2)      \
      KSR(P##v3, P##q3) KSR(P##v4, P##q4) KSR(P##v5, P##q5)      \
      KSR(P##v6, P##q6) KSR(P##v7, P##q7) RESC()                 \
    } else {                                                     \
      KSR(P##v0, P##q0)                                          \
      if ((rem) > 1) KSR(P##v1, P##q1)                           \
      if ((rem) > 2) KSR(P##v2, P##q2)                           \
      if ((rem) > 3) KSR(P##v3, P##q3)                           \
      if ((rem) > 4) KSR(P##v4, P##q4)                           \
      if ((rem) > 5) KSR(P##v5, P##q5)                           \
      if ((rem) > 6) KSR(P##v6, P##q6)                           \
      RESC()                                                     \
    }                                                            \
  } while (0)

template <int R0, int LAST>
__device__ __forceinline__ void k2_body(
    const float* __restrict__ gb, const int* __restrict__ targets,
    const int* __restrict__ in_len, const int* __restrict__ tgt_len,
    float* __restrict__ alpha_g, int* __restrict__ exp_g,
    float* __restrict__ tot, int b, int t0, int Tc, int S) {
  const int lane = threadIdx.x & 63;
  const int len = in_len[b];
  const int tl = tgt_len[b];
  const int* tg = targets + (size_t)b * S;
  const int4 mytg = *(const int4*)(tg + 4 * lane);
  const int tgm1 = (lane > 0) ? tg[4 * lane - 1] : -1;
  const float sk1 = (lane > 0 && mytg.x != tgm1) ? 1.f : 0.f;
  const float sk3 = (mytg.y != mytg.x) ? 1.f : 0.f;
  const float sk5 = (mytg.z != mytg.y) ? 1.f : 0.f;
  const float sk7 = (mytg.w != mytg.z) ? 1.f : 0.f;

  float a0 = 0.f, a1 = 0.f, a2 = 0.f, a3 = 0.f, a4 = 0.f, a5 = 0.f, a6 = 0.f,
        a7 = 0.f, a8 = 0.f;
  int E = 0;
  if (R0) {
    if (lane == 0) { a0 = gb[256]; a1 = gb[0]; }  // t=0: blank, first label
  } else {
    const float* ap = alpha_g + (size_t)b * 520 + 8 * lane;
    a0 = ap[0]; a1 = ap[1]; a2 = ap[2]; a3 = ap[3];
    a4 = ap[4]; a5 = ap[5]; a6 = ap[6]; a7 = ap[7];
    a8 = (lane == 63) ? alpha_g[(size_t)b * 520 + 512] : 0.f;
    E = exp_g[b];
  }

  const int t_hi = min(t0 + Tc, len);
  int N = t_hi - (t0 + R0);
  if (N < 0) N = 0;
  const int G = (N + 7) >> 3;

  const float* gpA_ = gb + (size_t)R0 * 272 + 4 * lane;
  const float* gqA_ = gb + (size_t)R0 * 272 + 256;
  const float* gpB_ = gpA_ + 1088;  // 4 rows ahead
  const float* gqB_ = gqA_ + 1088;

  DECL8(A) DECL8(B)

  __builtin_amdgcn_s_setprio(1);
  asm volatile("s_waitcnt vmcnt(0) lgkmcnt(0)" ::: "memory");
  SB();
  ISS8(A); ISS8(B);  // 32 vmem ops in flight (16-step prefetch)

  for (int g = 0; g < G; g += 2) {
    WAITV(16);
    COMP8(A, N - 8 * g);
    ISS8(A);
    if (g + 1 < G) {
      WAITV(16);
      COMP8(B, N - 8 * (g + 1));
      ISS8(B);
    }
  }
  WAITV(0);
  __builtin_amdgcn_s_setprio(0);

  if constexpr (LAST) {
    __shared__ float fin[520];
    fin[8 * lane + 0] = a0; fin[8 * lane + 1] = a1;
    fin[8 * lane + 2] = a2; fin[8 * lane + 3] = a3;
    fin[8 * lane + 4] = a4; fin[8 * lane + 5] = a5;
    fin[8 * lane + 6] = a6; fin[8 * lane + 7] = a7;
    if (lane == 63) fin[512] = a8;
    asm volatile("s_waitcnt lgkmcnt(0)" ::: "memory");
    SB();
    if (lane == 0) {
      const int i1 = 2 * tl;
      const int i2 = (2 * tl - 1 > 0) ? (2 * tl - 1) : 0;
      float v = fin[i1] + ((tl > 0) ? fin[i2] : 0.f);
      v = fmaxf(v, 1e-37f);
      tot[b] = logf(v) + (float)E * 0.6931471805599453f;
    }
  } else {
    float* ap = alpha_g + (size_t)b * 520 + 8 * lane;
    ap[0] = a0; ap[1] = a1; ap[2] = a2; ap[3] = a3;
    ap[4] = a4; ap[5] = a5; ap[6] = a6; ap[7] = a7;
    if (lane == 63) alpha_g[(size_t)b * 520 + 512] = a8;
    if (lane == 0) exp_g[b] = E;
  }
}

template <int R0, int LAST>
__global__ __launch_bounds__(64, 1) void k2_std(
    const float* __restrict__ gbuf, const int* __restrict__ targets,
    const int* __restrict__ in_len, const int* __restrict__ tgt_len,
    float* __restrict__ alpha_g, int* __restrict__ exp_g,
    float* __restrict__ tot, int t0, int Tc, int CB, int S) {
  k2_body<R0, LAST>(gbuf + (size_t)blockIdx.x * CB * 272, targets, in_len,
                    tgt_len, alpha_g, exp_g, tot, blockIdx.x, t0, Tc, S);
}

// ---------------- fused: k2 on chunk c-1 (blocks 0..63) || k1 on chunk c ----
template <int R0>
__global__ __launch_bounds__(256, 1) void fused_k(
    const float* __restrict__ lp, const int* __restrict__ targets,
    const int* __restrict__ in_len, const int* __restrict__ tgt_len,
    float* __restrict__ alpha_g, int* __restrict__ exp_g,
    float* __restrict__ tot, const float* __restrict__ gprev,
    float* __restrict__ gcur, int t0k2, int t0k1, int T, int Tc, int CB,
    int S, int TQ4) {
  __shared__ __align__(16) float rowbuf4[4][1024];
  if (blockIdx.x < 64) {
    if (threadIdx.x >= 64) return;
    k2_body<R0, 0>(gprev + (size_t)blockIdx.x * CB * 272, targets, in_len,
                   tgt_len, alpha_g, exp_g, tot, blockIdx.x, t0k2, Tc, S);
    return;
  }
  const int id = blockIdx.x - 64;
  const int b = id / TQ4;
  const int tq = id - b * TQ4;
  k1_body(lp, targets, gcur, t0k1, T, Tc, CB, S, b, tq,
          rowbuf4[threadIdx.x >> 6]);
}

// ---------------- k3: -mean over batch ----------------
__global__ void k3_mean(const float* __restrict__ tot, float* __restrict__ out,
                        int B) {
  float v = (threadIdx.x < B) ? tot[threadIdx.x] : 0.0f;
  v = wave_sum64(v);
  if (threadIdx.x == 0) out[0] = -v / (float)B;
}

// ---------------- host ----------------
extern "C" void kernel_launch(void* const* d_in, const int* in_sizes, int n_in,
                              void* d_out, int out_size, void* d_ws,
                              size_t ws_size, hipStream_t stream) {
  const float* lp = (const float*)d_in[0];
  const int* targets = (const int*)d_in[1];
  const int* in_len = (const int*)d_in[2];
  const int* tgt_len = (const int*)d_in[3];
  float* out = (float*)d_out;

  const int B = in_sizes[2];               // 64
  const int S = in_sizes[1] / B;           // 256
  const int C = 1024;
  const int T = (int)((size_t)in_sizes[0] / ((size_t)B * C));  // 2048

  const size_t headf = 64 + 64 + (size_t)64 * 520;
  int Tc = 512;                            // 4 chunks at T=2048
  if (Tc > T) Tc = T;
  while (Tc > 64) {
    const size_t need =
        headf * 4 + 2 * (size_t)64 * (Tc + 64) * 272 * 4;
    if (need <= ws_size) break;
    Tc >>= 1;
  }
  const int CB = Tc + 64;                  // pad rows cover 24-step over-read
  const int nch = (T + Tc - 1) / Tc;
  const int TQ4 = Tc / 4;

  float* tot = (float*)d_ws;
  int* exp_g = (int*)(tot + 64);
  float* alpha_g = (float*)(exp_g + 64);
  float* g0 = alpha_g + (size_t)64 * 520;
  const size_t BUF = (size_t)64 * CB * 272;
  float* gbuf[2] = {g0, g0 + BUF};

  if (nch == 1) {
    k1_std<<<dim3(TQ4, B), 256, 0, stream>>>(lp, targets, gbuf[0], 0, T, Tc,
                                             CB, S);
    k2_std<1, 1><<<B, 64, 0, stream>>>(gbuf[0], targets, in_len, tgt_len,
                                       alpha_g, exp_g, tot, 0, Tc, CB, S);
  } else {
    k1_std<<<dim3(TQ4, B), 256, 0, stream>>>(lp, targets, gbuf[0], 0, T, Tc,
                                             CB, S);
    for (int c = 1; c < nch; ++c) {
      const int t0k2 = (c - 1) * Tc;
      const int t0k1 = c * Tc;
      const dim3 grid(64 + TQ4 * B);
      if (c == 1)
        fused_k<1><<<grid, 256, 0, stream>>>(
            lp, targets, in_len, tgt_len, alpha_g, exp_g, tot,
            gbuf[(c - 1) & 1], gbuf[c & 1], t0k2, t0k1, T, Tc, CB, S, TQ4);
      else
        fused_k<0><<<grid, 256, 0, stream>>>(
            lp, targets, in_len, tgt_len, alpha_g, exp_g, tot,
            gbuf[(c - 1) & 1], gbuf[c & 1], t0k2, t0k1, T, Tc, CB, S, TQ4);
    }
    const int cl = nch - 1;
    k2_std<0, 1><<<B, 64, 0, stream>>>(gbuf[cl & 1], targets, in_len, tgt_len,
                                       alpha_g, exp_g, tot, cl * Tc, Tc, CB,
                                       S);
  }
  k3_mean<<<1, 64, 0, stream>>>(tot, out, B);
}